// Round 4
// baseline (863.365 us; speedup 1.0000x reference)
//
#include <hip/hip_runtime.h>
#include <hip/hip_bf16.h>

typedef unsigned short u16;
typedef short bf16x8 __attribute__((ext_vector_type(8)));
typedef float f32x4 __attribute__((ext_vector_type(4)));
typedef float f32x16 __attribute__((ext_vector_type(16)));
typedef float f4 __attribute__((ext_vector_type(4)));
typedef unsigned short u16x4 __attribute__((ext_vector_type(4)));

__device__ __forceinline__ u16 f2b(float f) {
    union { __hip_bfloat16 h; u16 u; } cv;
    cv.h = __float2bfloat16(f);
    return cv.u;
}
__device__ __forceinline__ float b2f(u16 u) {
    union { u16 u; __hip_bfloat16 h; } cv;
    cv.u = u;
    return __bfloat162float(cv.h);
}

// async 16B/lane global->LDS. lds base must be wave-uniform; HW scatters lane i to base + i*16.
__device__ __forceinline__ void g2l16(const void* g, void* l) {
    __builtin_amdgcn_global_load_lds(
        (const __attribute__((address_space(1))) unsigned int*)g,
        (__attribute__((address_space(3))) unsigned int*)l, 16, 0, 0);
}

// ---------------- weight ternarization: per-row absmean + ternary bf16 ----------------
// K = NV4*1024 + NS*256. float4 loads (16B/lane), ushort4 stores (8B/lane).
template <int NV4, int NS>
__global__ __launch_bounds__(256) void quant_kernel(const float* __restrict__ W,
                                                    u16* __restrict__ T,
                                                    float* __restrict__ scales, int K) {
    const int row = blockIdx.x, tid = threadIdx.x;
    const float* wr = W + (size_t)row * K;
    f4 v[NV4];
    float vs[NS];
    float s = 0.f;
#pragma unroll
    for (int j = 0; j < NV4; ++j) {
        v[j] = ((const f4*)wr)[tid + j * 256];
#pragma unroll
        for (int e = 0; e < 4; ++e) s += fabsf(v[j][e]);
    }
#pragma unroll
    for (int j = 0; j < NS; ++j) { vs[j] = wr[NV4 * 1024 + j * 256 + tid]; s += fabsf(vs[j]); }
#pragma unroll
    for (int d = 1; d < 64; d <<= 1) s += __shfl_xor(s, d);
    __shared__ float red[4];
    if ((tid & 63) == 0) red[tid >> 6] = s;
    __syncthreads();
    const float absmean = (red[0] + red[1] + red[2] + red[3]) / (float)K;
    const float thr = 0.7f * absmean;
    u16* tr = T + (size_t)row * K;
#pragma unroll
    for (int j = 0; j < NV4; ++j) {
        u16x4 o;
#pragma unroll
        for (int e = 0; e < 4; ++e) {
            const float w = v[j][e];
            o[e] = (fabsf(w) > thr) ? ((w > 0.f) ? (u16)0x3F80 : (u16)0xBF80) : (u16)0;
        }
        ((u16x4*)tr)[tid + j * 256] = o;
    }
#pragma unroll
    for (int j = 0; j < NS; ++j) {
        const float w = vs[j];
        tr[NV4 * 1024 + j * 256 + tid] = (fabsf(w) > thr) ? ((w > 0.f) ? (u16)0x3F80 : (u16)0xBF80) : (u16)0;
    }
    if (tid == 0) scales[row] = absmean;
}

// ---------------- rmsnorm: fp32 in -> bf16 out, row = 2560 (2x float4 + 2 scalar) ----------------
__global__ __launch_bounds__(256) void rmsnorm_kernel(const float* __restrict__ x,
                                                      const float* __restrict__ g,
                                                      u16* __restrict__ o) {
    const int row = blockIdx.x, tid = threadIdx.x;
    const float* xr = x + (size_t)row * 2560;
    f4 v[2];
    float vs[2];
    float s = 0.f;
#pragma unroll
    for (int j = 0; j < 2; ++j) {
        v[j] = ((const f4*)xr)[tid + j * 256];
#pragma unroll
        for (int e = 0; e < 4; ++e) s += v[j][e] * v[j][e];
    }
#pragma unroll
    for (int j = 0; j < 2; ++j) { vs[j] = xr[2048 + j * 256 + tid]; s += vs[j] * vs[j]; }
#pragma unroll
    for (int d = 1; d < 64; d <<= 1) s += __shfl_xor(s, d);
    __shared__ float red[4];
    if ((tid & 63) == 0) red[tid >> 6] = s;
    __syncthreads();
    const float total = red[0] + red[1] + red[2] + red[3];
    const float rs = rsqrtf(total * (1.f / 2560.f) + 1e-5f);
    u16* orow = o + (size_t)row * 2560;
#pragma unroll
    for (int j = 0; j < 2; ++j) {
        const f4 gv = ((const f4*)g)[tid + j * 256];
        u16x4 ov;
#pragma unroll
        for (int e = 0; e < 4; ++e) ov[e] = f2b(v[j][e] * rs * gv[e]);
        ((u16x4*)orow)[tid + j * 256] = ov;
    }
#pragma unroll
    for (int j = 0; j < 2; ++j)
        orow[2048 + j * 256 + tid] = f2b(vs[j] * rs * g[2048 + j * 256 + tid]);
}

// ---------------- GEMM: C[M,N] = A[M,K](bf16) x B[N,K](bf16 ternary, B^T layout) ----------------
// 512 threads, 128x128 tile, BK=64, wave sub-tile 64x32 via 2x mfma_f32_32x32x16_bf16.
// A/B frag: row/col = lane&31, k = (lane>>5)*8 + j. C/D: col = lane&31,
// row = (reg&3) + 8*(reg>>2) + 4*(lane>>5)  [HW-verified mapping].
// Chunk-XOR-swizzled LDS: elem (row,k) at row*64 + ((k>>3)^(row&7))*8 + (k&7).
// v4: double-buffered LDS (2x32KB, still 2 blocks/CU) with prefetch-before-compute and a
// SINGLE barrier per K-iter: the barrier's vmcnt(0) drain lands after 12 ds_reads + 8 MFMA,
// hiding global latency (same pipeline that fixed flash). XCD-chunked block swizzle (all
// grids %8==0) co-locates same-B-panel blocks on one XCD's L2.
// MODE 0: out bf16 = acc*scale[n].  MODE 1: out fp32 = res + acc*scale[n].
// MODE 2: out bf16 = relu(resg)^2 * acc*scale[n]  (glu fused into up-proj; resg = gate bf16).
template <int MODE>
__global__ __launch_bounds__(512, 4) void gemm_bt(const u16* __restrict__ A,
                                                  const u16* __restrict__ B,
                                                  const float* __restrict__ scale,
                                                  const float* res,
                                                  void* __restrict__ outp,
                                                  int M, int N, int K) {
    __shared__ __align__(16) u16 sA[2][128 * 64];
    __shared__ __align__(16) u16 sB[2][128 * 64];
    const int tid = threadIdx.x;
    const int wave = tid >> 6, lane = tid & 63;
    const int l31 = lane & 31, half = lane >> 5;

    // XCD-chunked bijective swizzle (nwg % 8 == 0 for every grid we launch)
    const int nwg = gridDim.x * gridDim.y;
    int lin = blockIdx.y * gridDim.x + blockIdx.x;
    lin = (lin & 7) * (nwg >> 3) + (lin >> 3);
    const int m0 = (lin % gridDim.x) * 128, n0 = (lin / gridDim.x) * 128;
    const int wm = wave >> 2, wn = wave & 3;  // wave tile: rows wm*64+, cols wn*32+

    f32x16 acc[2] = {};

    // staging: instr s covers 64 rows; chunk = s*512 + wave*64 + lane
    // row = s*64 + wave*8 + (lane>>3); phys chunk = lane&7; global chunk = (lane&7)^(row&7)
    const int r0 = wave * 8 + (lane >> 3);           // row&7 == lane>>3
    const int gcc = (lane & 7) ^ (lane >> 3);
    const size_t aoff = (size_t)(m0 + r0) * K + gcc * 8;
    const size_t boff = (size_t)(n0 + r0) * K + gcc * 8;
    const int swz = l31 & 7;  // fragment-read swizzle key (row&7 == l31&7)
    const int arow0 = (wm * 64 + l31) * 64;
    const int arow1 = (wm * 64 + 32 + l31) * 64;
    const int brow = (wn * 32 + l31) * 64;

    auto stage = [&](int kt, int b) {
        char* ldsA = (char*)(&sA[b][0]) + wave * 1024;
        char* ldsB = (char*)(&sB[b][0]) + wave * 1024;
        g2l16(A + aoff + kt, ldsA);
        g2l16(A + aoff + (size_t)64 * K + kt, ldsA + 8192);
        g2l16(B + boff + kt, ldsB);
        g2l16(B + boff + (size_t)64 * K + kt, ldsB + 8192);
    };

    stage(0, 0);
    __syncthreads();
    const int nk = K >> 6;
    for (int t = 0; t < nk; ++t) {
        const int buf = t & 1;
        if (t + 1 < nk) stage((t + 1) * 64, buf ^ 1);  // prefetch; drains at the barrier
        const u16* pA = &sA[buf][0];
        const u16* pB = &sB[buf][0];
#pragma unroll
        for (int ks = 0; ks < 4; ++ks) {
            const int pc = ((ks * 2 + half) ^ swz) * 8;
            const bf16x8 bfr = *(const bf16x8*)&pB[brow + pc];
            const bf16x8 a0 = *(const bf16x8*)&pA[arow0 + pc];
            const bf16x8 a1 = *(const bf16x8*)&pA[arow1 + pc];
            acc[0] = __builtin_amdgcn_mfma_f32_32x32x16_bf16(a0, bfr, acc[0], 0, 0, 0);
            acc[1] = __builtin_amdgcn_mfma_f32_32x32x16_bf16(a1, bfr, acc[1], 0, 0, 0);
        }
        __syncthreads();  // releases buf for overwrite + completes prefetch into buf^1
    }

    const int c = n0 + wn * 32 + l31;
    const float sc = scale[c];
#pragma unroll
    for (int mt = 0; mt < 2; ++mt) {
        const int rb = m0 + wm * 64 + mt * 32 + 4 * half;
#pragma unroll
        for (int r = 0; r < 16; ++r) {
            const int row = rb + (r & 3) + 8 * (r >> 2);
            const float vv = acc[mt][r] * sc;
            const size_t idx = (size_t)row * N + c;
            if (MODE == 0)      ((u16*)outp)[idx] = f2b(vv);
            else if (MODE == 1) ((float*)outp)[idx] = res[idx] + vv;
            else {
                const float gg = fmaxf(b2f(((const u16*)res)[idx]), 0.f);
                ((u16*)outp)[idx] = f2b(gg * gg * vv);
            }
        }
    }
}

// ---------------- RoPE in-place on [2048, stride] bf16, nh heads at given base ----------------
__global__ __launch_bounds__(256) void rope_kernel(u16* __restrict__ buf, int stride,
                                                   const float* __restrict__ cs,
                                                   const float* __restrict__ sn, int nh) {
    const int idx = blockIdx.x * 256 + threadIdx.x;
    const int d = idx & 63;
    const int h = (idx >> 6) % nh;
    const int s = idx / (64 * nh);
    const size_t base = (size_t)s * stride + h * 128;
    const float a = b2f(buf[base + d]), b = b2f(buf[base + d + 64]);
    const float c1 = cs[s * 128 + d], s1 = sn[s * 128 + d];
    const float c2 = cs[s * 128 + d + 64], s2 = sn[s * 128 + d + 64];
    buf[base + d] = f2b(a * c1 - b * s1);
    buf[base + d + 64] = f2b(b * c2 + a * s2);
}

// ---------------- V transpose: [2048, stride] (head h at col h*128) -> [5][128][2048] ----------------
__global__ __launch_bounds__(256) void transpose_v_kernel(const u16* __restrict__ V, int stride,
                                                          u16* __restrict__ VT) {
    __shared__ u16 t[128 * 66];
    const int tid = threadIdx.x;
    const int h = blockIdx.y, s0 = blockIdx.x * 64;
#pragma unroll
    for (int i = 0; i < 32; ++i) {
        const int idx = tid + i * 256;  // 64 s-rows x 128 d
        const int r = idx >> 7, c = idx & 127;
        t[c * 66 + r] = V[(size_t)(s0 + r) * stride + h * 128 + c];
    }
    __syncthreads();
#pragma unroll
    for (int i = 0; i < 32; ++i) {
        const int idx = tid + i * 256;  // 128 d-rows x 64 s
        const int d = idx >> 6, s = idx & 63;
        VT[((size_t)h * 128 + d) * 2048 + s0 + s] = t[d * 66 + s];
    }
}

// ---------------- flash attention: 20 heads, GQA 4:1, S=2048, D=128, non-causal ----------------
// 64 q-rows/block (wave owns 16), 32-key tiles, exp2-domain online softmax.
// Double-buffered K/V at 32-key granularity: total LDS 48KB -> 3 blocks/CU. Prefetch of
// tile t+1 issued before compute of tile t; single end-of-tile barrier.
// Softmax: per-lane partial denominators + defer-max (THR=8 exp2 domain). P at row
// stride 40 u16. XCD-chunked block swizzle: same-head q-blocks (shared 2MB K/V working
// set, fits a 4MB XCD L2) co-locate on one XCD.
__global__ __launch_bounds__(256, 3) void flash_kernel(const u16* __restrict__ Q, int qs,
                                                       const u16* __restrict__ Kb,
                                                       const u16* __restrict__ VT,
                                                       u16* __restrict__ O) {
    __shared__ __align__(16) u16 sQ[64 * 128];     // 16KB; reused as sP (64 rows, stride 40)
    __shared__ __align__(16) u16 sK[2][32 * 128];  // 2x8KB
    __shared__ __align__(16) u16 sV[2][128 * 32];  // 2x8KB, V^T tile [d][key]
    const int tid = threadIdx.x, wave = tid >> 6, lane = tid & 63;
    const int lane15 = lane & 15, quad = lane >> 4;
    // grid is fixed (32, 20) = 640 blocks; chunked XCD swizzle (640/8 = 80)
    int lin = blockIdx.y * 32 + blockIdx.x;
    lin = (lin & 7) * 80 + (lin >> 3);
    const int head = lin >> 5, q0 = (lin & 31) * 64, kvh = head >> 2;
    const int sw = lane15 & 7;

    const int rk = wave * 4 + (lane >> 4);
    const int gk = (lane & 15) ^ (rk & 7);
    const u16* kbase = Kb + (size_t)rk * qs + kvh * 128 + gk * 8;
    const int rv = wave * 16 + (lane >> 2);
    const int gv = (lane & 3) ^ ((lane >> 3) & 3);
    const u16* vbase = VT + ((size_t)kvh * 128 + rv) * 2048 + gv * 8;

    auto stage = [&](int k0, int b) {
        char* dK = (char*)(&sK[b][0]) + wave * 1024;
        char* dV = (char*)(&sV[b][0]) + wave * 1024;
#pragma unroll
        for (int s = 0; s < 2; ++s) {
            g2l16(kbase + ((size_t)k0 + s * 16) * qs, dK + s * 4096);
            g2l16(vbase + (size_t)s * 64 * 2048 + k0, dV + s * 4096);
        }
    };

    {   // stage Q + first K/V tile together (one exposed latency event)
        const int rq = wave * 4 + (lane >> 4);
        const int gq = (lane & 15) ^ (rq & 7);
        const u16* src = Q + (size_t)(q0 + rq) * qs + head * 128 + gq * 8;
        char* dst = (char*)sQ + wave * 1024;
#pragma unroll
        for (int s = 0; s < 4; ++s)
            g2l16(src + (size_t)s * 16 * qs, dst + s * 4096);
        stage(0, 0);
    }
    __syncthreads();
    bf16x8 qf[4];
#pragma unroll
    for (int kc = 0; kc < 4; ++kc)
        qf[kc] = *(const bf16x8*)&sQ[(wave * 16 + lane15) * 128 + ((kc * 4 + quad) ^ sw) * 8];

    float m_i[4], lp[4];
    f32x4 o_acc[8] = {};
#pragma unroll
    for (int r = 0; r < 4; ++r) { m_i[r] = -1e30f; lp[r] = 0.f; }

    const float sl2e = 0.088388347648318447f * 1.4426950408889634f;  // 1/sqrt(128) * log2(e)
    const float THR = 8.0f;  // defer-max threshold (exp2 domain)
    u16* sP = sQ;  // P tile: 64 rows x 32 keys, stride 40 u16 (5120B, fits in sQ)

    for (int t = 0; t < 64; ++t) {
        const int buf = t & 1;
        if (t < 63) stage((t + 1) * 32, buf ^ 1);  // prefetch next tile; drains at the barrier
        const u16* sKb = &sK[buf][0];
        const u16* sVb = &sV[buf][0];

        // S = Q K^T : wave's 16 q-rows x 32 keys
        f32x4 sacc[2] = {};
        __builtin_amdgcn_s_setprio(1);
#pragma unroll
        for (int nf = 0; nf < 2; ++nf)
#pragma unroll
            for (int kc = 0; kc < 4; ++kc) {
                const bf16x8 kf = *(const bf16x8*)&sKb[(nf * 16 + lane15) * 128 + ((kc * 4 + quad) ^ sw) * 8];
                sacc[nf] = __builtin_amdgcn_mfma_f32_16x16x32_bf16(qf[kc], kf, sacc[nf], 0, 0, 0);
            }
        __builtin_amdgcn_s_setprio(0);

        float mx[4];
#pragma unroll
        for (int r = 0; r < 4; ++r) {
            float v0 = sacc[0][r] * sl2e, v1 = sacc[1][r] * sl2e;
            sacc[0][r] = v0; sacc[1][r] = v1;
            float m0 = fmaxf(v0, v1);
#pragma unroll
            for (int d = 1; d < 16; d <<= 1) m0 = fmaxf(m0, __shfl_xor(m0, d));
            mx[r] = m0;
        }
        const int upd = (mx[0] > m_i[0] + THR) | (mx[1] > m_i[1] + THR) |
                        (mx[2] > m_i[2] + THR) | (mx[3] > m_i[3] + THR);
        if (__any(upd)) {
#pragma unroll
            for (int r = 0; r < 4; ++r) {
                const float mnew = fmaxf(m_i[r], mx[r]);
                const float alpha = exp2f(m_i[r] - mnew);
                m_i[r] = mnew;
                lp[r] *= alpha;
#pragma unroll
                for (int nf = 0; nf < 8; ++nf) o_acc[nf][r] *= alpha;
            }
        }
#pragma unroll
        for (int r = 0; r < 4; ++r) {
            const float m = m_i[r];
            const float p0 = exp2f(sacc[0][r] - m), p1 = exp2f(sacc[1][r] - m);
            sacc[0][r] = p0; sacc[1][r] = p1;
            lp[r] += p0 + p1;
        }

        // P -> sP (own 16 rows; same-wave DS ops are ordered). Linear cols, stride 40.
#pragma unroll
        for (int nf = 0; nf < 2; ++nf) {
            const int pcol = nf * 16 + lane15;
#pragma unroll
            for (int r = 0; r < 4; ++r)
                sP[(wave * 16 + quad * 4 + r) * 40 + pcol] = f2b(sacc[nf][r]);
        }

        // O += P V
        const bf16x8 pf = *(const bf16x8*)&sP[(wave * 16 + lane15) * 40 + quad * 8];
        __builtin_amdgcn_s_setprio(1);
#pragma unroll
        for (int nf = 0; nf < 8; ++nf) {
            const bf16x8 vf = *(const bf16x8*)&sVb[(nf * 16 + lane15) * 32 +
                                                   ((quad ^ ((lane15 >> 1) & 3))) * 8];
            o_acc[nf] = __builtin_amdgcn_mfma_f32_16x16x32_bf16(pf, vf, o_acc[nf], 0, 0, 0);
        }
        __builtin_amdgcn_s_setprio(0);
        __syncthreads();
    }

#pragma unroll
    for (int r = 0; r < 4; ++r) {
        float lt = lp[r];
#pragma unroll
        for (int d = 1; d < 16; d <<= 1) lt += __shfl_xor(lt, d);
        const float inv = 1.f / lt;
        const int row = q0 + wave * 16 + quad * 4 + r;
        u16* orow = O + (size_t)row * 2560 + head * 128;
#pragma unroll
        for (int nf = 0; nf < 8; ++nf)
            orow[nf * 16 + lane15] = f2b(o_acc[nf][r] * inv);
    }
}

extern "C" void kernel_launch(void* const* d_in, const int* in_sizes, int n_in,
                              void* d_out, int out_size, void* d_ws, size_t ws_size,
                              hipStream_t stream) {
    (void)in_sizes; (void)n_in; (void)out_size; (void)ws_size;
    const float* x      = (const float*)d_in[0];
    const float* cosb   = (const float*)d_in[1];
    const float* sinb   = (const float*)d_in[2];
    const float* q_w    = (const float*)d_in[3];
    const float* k_w    = (const float*)d_in[4];
    const float* v_w    = (const float*)d_in[5];
    const float* o_w    = (const float*)d_in[6];
    const float* gate_w = (const float*)d_in[7];
    const float* up_w   = (const float*)d_in[8];
    const float* down_w = (const float*)d_in[9];
    const float* ln1    = (const float*)d_in[10];
    const float* ln2    = (const float*)d_in[11];

    char* w = (char*)d_ws;
    size_t off = 0;
    auto nxt = [&](size_t sz) { char* p = w + off; off += sz; return p; };
    u16*   TQ = (u16*)nxt(13107200);   // q ternary  [2560,2560]   } contiguous => fused
    u16*   TK = (u16*)nxt(3276800);    // k ternary  [640,2560]    }  qkv B-matrix
    u16*   TV = (u16*)nxt(3276800);    // v ternary  [640,2560]    }  [3840,2560]
    u16*   TO = (u16*)nxt(13107200);   // o ternary  [2560,2560]
    u16*   TB = (u16*)nxt(35389440);   // shared big ternary (gate/up/down, quantized just-in-time)
    float* SC = (float*)nxt(91136);    // scales: q@0 k@2560 v@3200 o@3840 g@6400 u@13312 d@20224
    u16*   H  = (u16*)nxt(10485760);   // rmsnorm out bf16 [2048,2560]; reused as attn out and h2
    u16*   QKV = (u16*)nxt(15728640);  // fused qkv proj bf16 [2048,3840] (q|k|v per row)
    u16*   VT = (u16*)nxt(2621440);    // v transposed [5][128][2048]
    float* XM = (float*)nxt(20971520); // x after o-proj residual, fp32 [2048,2560]
    u16*   G  = (u16*)nxt(28311552);   // gate out bf16 [2048,6912]; becomes t in place (MODE2 up)

    // --- attention path ---
    quant_kernel<2, 2><<<2560, 256, 0, stream>>>(q_w, TQ, SC + 0, 2560);
    quant_kernel<2, 2><<<640, 256, 0, stream>>>(k_w, TK, SC + 2560, 2560);
    quant_kernel<2, 2><<<640, 256, 0, stream>>>(v_w, TV, SC + 3200, 2560);
    quant_kernel<2, 2><<<2560, 256, 0, stream>>>(o_w, TO, SC + 3840, 2560);
    rmsnorm_kernel<<<2048, 256, 0, stream>>>(x, ln1, H);
    gemm_bt<0><<<dim3(16, 30), 512, 0, stream>>>(H, TQ, SC + 0, nullptr, QKV, 2048, 3840, 2560);
    rope_kernel<<<10240, 256, 0, stream>>>(QKV, 3840, cosb, sinb, 20);           // q cols 0..2559
    rope_kernel<<<2560, 256, 0, stream>>>(QKV + 2560, 3840, cosb, sinb, 5);      // k cols 2560..3199
    transpose_v_kernel<<<dim3(32, 5), 256, 0, stream>>>(QKV + 3200, 3840, VT);   // v cols 3200..3839
    flash_kernel<<<dim3(32, 20), 256, 0, stream>>>(QKV, 3840, QKV + 2560, VT, H);
    gemm_bt<1><<<dim3(16, 20), 512, 0, stream>>>(H, TO, SC + 3840, x, XM, 2048, 2560, 2560);

    // --- MLP path ---
    rmsnorm_kernel<<<2048, 256, 0, stream>>>(XM, ln2, H);
    quant_kernel<2, 2><<<6912, 256, 0, stream>>>(gate_w, TB, SC + 6400, 2560);
    gemm_bt<0><<<dim3(16, 54), 512, 0, stream>>>(H, TB, SC + 6400, nullptr, G, 2048, 6912, 2560);
    quant_kernel<2, 2><<<6912, 256, 0, stream>>>(up_w, TB, SC + 13312, 2560);
    // up-proj with fused glu epilogue: G[idx] = relu(G[idx])^2 * (acc*scale)
    gemm_bt<2><<<dim3(16, 54), 512, 0, stream>>>(H, TB, SC + 13312, (const float*)G, G, 2048, 6912, 2560);
    quant_kernel<6, 3><<<2560, 256, 0, stream>>>(down_w, TB, SC + 20224, 6912);
    gemm_bt<1><<<dim3(16, 20), 512, 0, stream>>>(G, TB, SC + 20224, XM, (float*)d_out, 2048, 2560, 6912);
}

// Round 5
// 862.297 us; speedup vs baseline: 1.0012x; 1.0012x over previous
//
#include <hip/hip_runtime.h>
#include <hip/hip_bf16.h>

typedef unsigned short u16;
typedef short bf16x8 __attribute__((ext_vector_type(8)));
typedef float f32x4 __attribute__((ext_vector_type(4)));
typedef float f32x16 __attribute__((ext_vector_type(16)));
typedef float f4 __attribute__((ext_vector_type(4)));
typedef unsigned short u16x4 __attribute__((ext_vector_type(4)));

__device__ __forceinline__ u16 f2b(float f) {
    union { __hip_bfloat16 h; u16 u; } cv;
    cv.h = __float2bfloat16(f);
    return cv.u;
}
__device__ __forceinline__ float b2f(u16 u) {
    union { u16 u; __hip_bfloat16 h; } cv;
    cv.u = u;
    return __bfloat162float(cv.h);
}

// async 16B/lane global->LDS. lds base must be wave-uniform; HW scatters lane i to base + i*16.
__device__ __forceinline__ void g2l16(const void* g, void* l) {
    __builtin_amdgcn_global_load_lds(
        (const __attribute__((address_space(1))) unsigned int*)g,
        (__attribute__((address_space(3))) unsigned int*)l, 16, 0, 0);
}

// ---------------- weight ternarization: per-row absmean + ternary bf16 ----------------
// K = NV4*1024 + NS*256. float4 loads (16B/lane), ushort4 stores (8B/lane).
template <int NV4, int NS>
__global__ __launch_bounds__(256) void quant_kernel(const float* __restrict__ W,
                                                    u16* __restrict__ T,
                                                    float* __restrict__ scales, int K) {
    const int row = blockIdx.x, tid = threadIdx.x;
    const float* wr = W + (size_t)row * K;
    f4 v[NV4];
    float vs[NS];
    float s = 0.f;
#pragma unroll
    for (int j = 0; j < NV4; ++j) {
        v[j] = ((const f4*)wr)[tid + j * 256];
#pragma unroll
        for (int e = 0; e < 4; ++e) s += fabsf(v[j][e]);
    }
#pragma unroll
    for (int j = 0; j < NS; ++j) { vs[j] = wr[NV4 * 1024 + j * 256 + tid]; s += fabsf(vs[j]); }
#pragma unroll
    for (int d = 1; d < 64; d <<= 1) s += __shfl_xor(s, d);
    __shared__ float red[4];
    if ((tid & 63) == 0) red[tid >> 6] = s;
    __syncthreads();
    const float absmean = (red[0] + red[1] + red[2] + red[3]) / (float)K;
    const float thr = 0.7f * absmean;
    u16* tr = T + (size_t)row * K;
#pragma unroll
    for (int j = 0; j < NV4; ++j) {
        u16x4 o;
#pragma unroll
        for (int e = 0; e < 4; ++e) {
            const float w = v[j][e];
            o[e] = (fabsf(w) > thr) ? ((w > 0.f) ? (u16)0x3F80 : (u16)0xBF80) : (u16)0;
        }
        ((u16x4*)tr)[tid + j * 256] = o;
    }
#pragma unroll
    for (int j = 0; j < NS; ++j) {
        const float w = vs[j];
        tr[NV4 * 1024 + j * 256 + tid] = (fabsf(w) > thr) ? ((w > 0.f) ? (u16)0x3F80 : (u16)0xBF80) : (u16)0;
    }
    if (tid == 0) scales[row] = absmean;
}

// ---------------- rmsnorm: fp32 in -> bf16 out, row = 2560 (2x float4 + 2 scalar) ----------------
__global__ __launch_bounds__(256) void rmsnorm_kernel(const float* __restrict__ x,
                                                      const float* __restrict__ g,
                                                      u16* __restrict__ o) {
    const int row = blockIdx.x, tid = threadIdx.x;
    const float* xr = x + (size_t)row * 2560;
    f4 v[2];
    float vs[2];
    float s = 0.f;
#pragma unroll
    for (int j = 0; j < 2; ++j) {
        v[j] = ((const f4*)xr)[tid + j * 256];
#pragma unroll
        for (int e = 0; e < 4; ++e) s += v[j][e] * v[j][e];
    }
#pragma unroll
    for (int j = 0; j < 2; ++j) { vs[j] = xr[2048 + j * 256 + tid]; s += vs[j] * vs[j]; }
#pragma unroll
    for (int d = 1; d < 64; d <<= 1) s += __shfl_xor(s, d);
    __shared__ float red[4];
    if ((tid & 63) == 0) red[tid >> 6] = s;
    __syncthreads();
    const float total = red[0] + red[1] + red[2] + red[3];
    const float rs = rsqrtf(total * (1.f / 2560.f) + 1e-5f);
    u16* orow = o + (size_t)row * 2560;
#pragma unroll
    for (int j = 0; j < 2; ++j) {
        const f4 gv = ((const f4*)g)[tid + j * 256];
        u16x4 ov;
#pragma unroll
        for (int e = 0; e < 4; ++e) ov[e] = f2b(v[j][e] * rs * gv[e]);
        ((u16x4*)orow)[tid + j * 256] = ov;
    }
#pragma unroll
    for (int j = 0; j < 2; ++j)
        orow[2048 + j * 256 + tid] = f2b(vs[j] * rs * g[2048 + j * 256 + tid]);
}

// ---------------- GEMM: C[M,N] = A[M,K](bf16) x B[N,K](bf16 ternary, B^T layout) ----------------
// 512 threads, BK=64, tile = (128*NFR) x 128, single-buffered 2-barrier (round-4 showed
// dbuf+prefetch is neutral at 2 blocks/CU: cross-block TLP already covers staging latency).
// NFR=1: 128x128 tile, waves 2m x 4n, wave tile 64x32  (12 ds_read / 8 MFMA per K-step).
// NFR=2: 256x128 tile, waves 4m x 2n, wave tile 64x64  (16 ds_read / 16 MFMA per K-step:
//        1.5x less LDS-read traffic per MFMA — the 2-phase-structure lever).
// A/B frag: row/col = lane&31, k = (lane>>5)*8 + j. C/D: col = lane&31,
// row = (reg&3) + 8*(reg>>2) + 4*(lane>>5)  [HW-verified mapping].
// Chunk-XOR-swizzled LDS: elem (row,k) at row*64 + ((k>>3)^(row&7))*8 + (k&7).
// XCD-chunked block swizzle (all grids %8==0) keeps ~same-B-panel blocks per XCD L2.
// MODE 0: out bf16 = acc*scale[n].  MODE 1: out fp32 = res + acc*scale[n].
// MODE 2: out bf16 = relu(resg)^2 * acc*scale[n]  (glu fused into up-proj; resg = gate bf16).
template <int MODE, int NFR>
__global__ __launch_bounds__(512, 4) void gemm_bt(const u16* __restrict__ A,
                                                  const u16* __restrict__ B,
                                                  const float* __restrict__ scale,
                                                  const float* res,
                                                  void* __restrict__ outp,
                                                  int M, int N, int K) {
    constexpr int TM = 128 * NFR;
    __shared__ __align__(16) u16 sA[TM * 64];
    __shared__ __align__(16) u16 sB[128 * 64];
    const int tid = threadIdx.x;
    const int wave = tid >> 6, lane = tid & 63;
    const int l31 = lane & 31, half = lane >> 5;

    // XCD-chunked bijective swizzle (nwg % 8 == 0 for every grid we launch)
    const int nwg = gridDim.x * gridDim.y;
    int lin = blockIdx.y * gridDim.x + blockIdx.x;
    lin = (lin & 7) * (nwg >> 3) + (lin >> 3);
    const int m0 = (lin % gridDim.x) * TM, n0 = (lin / gridDim.x) * 128;
    const int wm = (NFR == 2) ? (wave >> 1) : (wave >> 2);
    const int wn = (NFR == 2) ? (wave & 1) : (wave & 3);

    f32x16 acc[2][NFR] = {};

    // staging: instr s covers 64 rows; chunk = s*512 + wave*64 + lane
    // row = s*64 + wave*8 + (lane>>3); phys chunk = lane&7; global chunk = (lane&7)^(row&7)
    const int r0 = wave * 8 + (lane >> 3);           // row&7 == lane>>3
    const int gcc = (lane & 7) ^ (lane >> 3);
    const size_t aoff = (size_t)(m0 + r0) * K + gcc * 8;
    const size_t boff = (size_t)(n0 + r0) * K + gcc * 8;
    const int swz = l31 & 7;  // fragment-read swizzle key (row&7 == l31&7)
    char* ldsA = (char*)sA + wave * 1024;
    char* ldsB = (char*)sB + wave * 1024;

    for (int kt = 0; kt < K; kt += 64) {
#pragma unroll
        for (int s = 0; s < TM / 64; ++s)
            g2l16(A + aoff + (size_t)(s * 64) * K + kt, ldsA + s * 8192);
#pragma unroll
        for (int s = 0; s < 2; ++s)
            g2l16(B + boff + (size_t)(s * 64) * K + kt, ldsB + s * 8192);
        __syncthreads();
#pragma unroll
        for (int ks = 0; ks < 4; ++ks) {
            const int pc = ((ks * 2 + half) ^ swz) * 8;
            bf16x8 af[2], bfr[NFR];
            af[0] = *(const bf16x8*)&sA[(wm * 64 + l31) * 64 + pc];
            af[1] = *(const bf16x8*)&sA[(wm * 64 + 32 + l31) * 64 + pc];
            if (NFR == 1) {
                bfr[0] = *(const bf16x8*)&sB[(wn * 32 + l31) * 64 + pc];
            } else {
                bfr[0] = *(const bf16x8*)&sB[(wn * 64 + l31) * 64 + pc];
                bfr[1] = *(const bf16x8*)&sB[(wn * 64 + 32 + l31) * 64 + pc];
            }
#pragma unroll
            for (int mt = 0; mt < 2; ++mt)
#pragma unroll
                for (int nt = 0; nt < NFR; ++nt)
                    acc[mt][nt] = __builtin_amdgcn_mfma_f32_32x32x16_bf16(af[mt], bfr[nt], acc[mt][nt], 0, 0, 0);
        }
        __syncthreads();
    }

#pragma unroll
    for (int nt = 0; nt < NFR; ++nt) {
        const int c = n0 + ((NFR == 1) ? wn * 32 : wn * 64 + nt * 32) + l31;
        const float sc = scale[c];
#pragma unroll
        for (int mt = 0; mt < 2; ++mt) {
            const int rb = m0 + wm * 64 + mt * 32 + 4 * half;
#pragma unroll
            for (int r = 0; r < 16; ++r) {
                const int row = rb + (r & 3) + 8 * (r >> 2);
                const float vv = acc[mt][nt][r] * sc;
                const size_t idx = (size_t)row * N + c;
                if (MODE == 0)      ((u16*)outp)[idx] = f2b(vv);
                else if (MODE == 1) ((float*)outp)[idx] = res[idx] + vv;
                else {
                    const float gg = fmaxf(b2f(((const u16*)res)[idx]), 0.f);
                    ((u16*)outp)[idx] = f2b(gg * gg * vv);
                }
            }
        }
    }
}

// ---------------- RoPE in-place on [2048, stride] bf16, nh heads at given base ----------------
__global__ __launch_bounds__(256) void rope_kernel(u16* __restrict__ buf, int stride,
                                                   const float* __restrict__ cs,
                                                   const float* __restrict__ sn, int nh) {
    const int idx = blockIdx.x * 256 + threadIdx.x;
    const int d = idx & 63;
    const int h = (idx >> 6) % nh;
    const int s = idx / (64 * nh);
    const size_t base = (size_t)s * stride + h * 128;
    const float a = b2f(buf[base + d]), b = b2f(buf[base + d + 64]);
    const float c1 = cs[s * 128 + d], s1 = sn[s * 128 + d];
    const float c2 = cs[s * 128 + d + 64], s2 = sn[s * 128 + d + 64];
    buf[base + d] = f2b(a * c1 - b * s1);
    buf[base + d + 64] = f2b(b * c2 + a * s2);
}

// ---------------- V transpose: [2048, stride] (head h at col h*128) -> [5][128][2048] ----------------
__global__ __launch_bounds__(256) void transpose_v_kernel(const u16* __restrict__ V, int stride,
                                                          u16* __restrict__ VT) {
    __shared__ u16 t[128 * 66];
    const int tid = threadIdx.x;
    const int h = blockIdx.y, s0 = blockIdx.x * 64;
#pragma unroll
    for (int i = 0; i < 32; ++i) {
        const int idx = tid + i * 256;  // 64 s-rows x 128 d
        const int r = idx >> 7, c = idx & 127;
        t[c * 66 + r] = V[(size_t)(s0 + r) * stride + h * 128 + c];
    }
    __syncthreads();
#pragma unroll
    for (int i = 0; i < 32; ++i) {
        const int idx = tid + i * 256;  // 128 d-rows x 64 s
        const int d = idx >> 6, s = idx & 63;
        VT[((size_t)h * 128 + d) * 2048 + s0 + s] = t[d * 66 + s];
    }
}

// ---------------- flash attention: 20 heads, GQA 4:1, S=2048, D=128, non-causal ----------------
// 64 q-rows/block (wave owns 16), 32-key tiles, exp2-domain online softmax.
// Double-buffered K/V at 32-key granularity: total LDS 48KB -> 3 blocks/CU. Prefetch of
// tile t+1 issued before compute of tile t; single end-of-tile barrier.
// Softmax: per-lane partial denominators + defer-max (THR=8 exp2 domain). P at row
// stride 40 u16. NO XCD swizzle: round-4 showed concentrating same-head blocks on one
// XCD cut FETCH 2.3x but slowed the kernel 5% (L2 serialization) — default mapping wins.
__global__ __launch_bounds__(256, 3) void flash_kernel(const u16* __restrict__ Q, int qs,
                                                       const u16* __restrict__ Kb,
                                                       const u16* __restrict__ VT,
                                                       u16* __restrict__ O) {
    __shared__ __align__(16) u16 sQ[64 * 128];     // 16KB; reused as sP (64 rows, stride 40)
    __shared__ __align__(16) u16 sK[2][32 * 128];  // 2x8KB
    __shared__ __align__(16) u16 sV[2][128 * 32];  // 2x8KB, V^T tile [d][key]
    const int tid = threadIdx.x, wave = tid >> 6, lane = tid & 63;
    const int lane15 = lane & 15, quad = lane >> 4;
    const int head = blockIdx.y, q0 = blockIdx.x * 64, kvh = head >> 2;
    const int sw = lane15 & 7;

    const int rk = wave * 4 + (lane >> 4);
    const int gk = (lane & 15) ^ (rk & 7);
    const u16* kbase = Kb + (size_t)rk * qs + kvh * 128 + gk * 8;
    const int rv = wave * 16 + (lane >> 2);
    const int gv = (lane & 3) ^ ((lane >> 3) & 3);
    const u16* vbase = VT + ((size_t)kvh * 128 + rv) * 2048 + gv * 8;

    auto stage = [&](int k0, int b) {
        char* dK = (char*)(&sK[b][0]) + wave * 1024;
        char* dV = (char*)(&sV[b][0]) + wave * 1024;
#pragma unroll
        for (int s = 0; s < 2; ++s) {
            g2l16(kbase + ((size_t)k0 + s * 16) * qs, dK + s * 4096);
            g2l16(vbase + (size_t)s * 64 * 2048 + k0, dV + s * 4096);
        }
    };

    {   // stage Q + first K/V tile together (one exposed latency event)
        const int rq = wave * 4 + (lane >> 4);
        const int gq = (lane & 15) ^ (rq & 7);
        const u16* src = Q + (size_t)(q0 + rq) * qs + head * 128 + gq * 8;
        char* dst = (char*)sQ + wave * 1024;
#pragma unroll
        for (int s = 0; s < 4; ++s)
            g2l16(src + (size_t)s * 16 * qs, dst + s * 4096);
        stage(0, 0);
    }
    __syncthreads();
    bf16x8 qf[4];
#pragma unroll
    for (int kc = 0; kc < 4; ++kc)
        qf[kc] = *(const bf16x8*)&sQ[(wave * 16 + lane15) * 128 + ((kc * 4 + quad) ^ sw) * 8];

    float m_i[4], lp[4];
    f32x4 o_acc[8] = {};
#pragma unroll
    for (int r = 0; r < 4; ++r) { m_i[r] = -1e30f; lp[r] = 0.f; }

    const float sl2e = 0.088388347648318447f * 1.4426950408889634f;  // 1/sqrt(128) * log2(e)
    const float THR = 8.0f;  // defer-max threshold (exp2 domain)
    u16* sP = sQ;  // P tile: 64 rows x 32 keys, stride 40 u16 (5120B, fits in sQ)

    for (int t = 0; t < 64; ++t) {
        const int buf = t & 1;
        if (t < 63) stage((t + 1) * 32, buf ^ 1);  // prefetch next tile; drains at the barrier
        const u16* sKb = &sK[buf][0];
        const u16* sVb = &sV[buf][0];

        // S = Q K^T : wave's 16 q-rows x 32 keys
        f32x4 sacc[2] = {};
        __builtin_amdgcn_s_setprio(1);
#pragma unroll
        for (int nf = 0; nf < 2; ++nf)
#pragma unroll
            for (int kc = 0; kc < 4; ++kc) {
                const bf16x8 kf = *(const bf16x8*)&sKb[(nf * 16 + lane15) * 128 + ((kc * 4 + quad) ^ sw) * 8];
                sacc[nf] = __builtin_amdgcn_mfma_f32_16x16x32_bf16(qf[kc], kf, sacc[nf], 0, 0, 0);
            }
        __builtin_amdgcn_s_setprio(0);

        float mx[4];
#pragma unroll
        for (int r = 0; r < 4; ++r) {
            float v0 = sacc[0][r] * sl2e, v1 = sacc[1][r] * sl2e;
            sacc[0][r] = v0; sacc[1][r] = v1;
            float m0 = fmaxf(v0, v1);
#pragma unroll
            for (int d = 1; d < 16; d <<= 1) m0 = fmaxf(m0, __shfl_xor(m0, d));
            mx[r] = m0;
        }
        const int upd = (mx[0] > m_i[0] + THR) | (mx[1] > m_i[1] + THR) |
                        (mx[2] > m_i[2] + THR) | (mx[3] > m_i[3] + THR);
        if (__any(upd)) {
#pragma unroll
            for (int r = 0; r < 4; ++r) {
                const float mnew = fmaxf(m_i[r], mx[r]);
                const float alpha = exp2f(m_i[r] - mnew);
                m_i[r] = mnew;
                lp[r] *= alpha;
#pragma unroll
                for (int nf = 0; nf < 8; ++nf) o_acc[nf][r] *= alpha;
            }
        }
#pragma unroll
        for (int r = 0; r < 4; ++r) {
            const float m = m_i[r];
            const float p0 = exp2f(sacc[0][r] - m), p1 = exp2f(sacc[1][r] - m);
            sacc[0][r] = p0; sacc[1][r] = p1;
            lp[r] += p0 + p1;
        }

        // P -> sP (own 16 rows; same-wave DS ops are ordered). Linear cols, stride 40.
#pragma unroll
        for (int nf = 0; nf < 2; ++nf) {
            const int pcol = nf * 16 + lane15;
#pragma unroll
            for (int r = 0; r < 4; ++r)
                sP[(wave * 16 + quad * 4 + r) * 40 + pcol] = f2b(sacc[nf][r]);
        }

        // O += P V
        const bf16x8 pf = *(const bf16x8*)&sP[(wave * 16 + lane15) * 40 + quad * 8];
        __builtin_amdgcn_s_setprio(1);
#pragma unroll
        for (int nf = 0; nf < 8; ++nf) {
            const bf16x8 vf = *(const bf16x8*)&sVb[(nf * 16 + lane15) * 32 +
                                                   ((quad ^ ((lane15 >> 1) & 3))) * 8];
            o_acc[nf] = __builtin_amdgcn_mfma_f32_16x16x32_bf16(pf, vf, o_acc[nf], 0, 0, 0);
        }
        __builtin_amdgcn_s_setprio(0);
        __syncthreads();
    }

#pragma unroll
    for (int r = 0; r < 4; ++r) {
        float lt = lp[r];
#pragma unroll
        for (int d = 1; d < 16; d <<= 1) lt += __shfl_xor(lt, d);
        const float inv = 1.f / lt;
        const int row = q0 + wave * 16 + quad * 4 + r;
        u16* orow = O + (size_t)row * 2560 + head * 128;
#pragma unroll
        for (int nf = 0; nf < 8; ++nf)
            orow[nf * 16 + lane15] = f2b(o_acc[nf][r] * inv);
    }
}

extern "C" void kernel_launch(void* const* d_in, const int* in_sizes, int n_in,
                              void* d_out, int out_size, void* d_ws, size_t ws_size,
                              hipStream_t stream) {
    (void)in_sizes; (void)n_in; (void)out_size; (void)ws_size;
    const float* x      = (const float*)d_in[0];
    const float* cosb   = (const float*)d_in[1];
    const float* sinb   = (const float*)d_in[2];
    const float* q_w    = (const float*)d_in[3];
    const float* k_w    = (const float*)d_in[4];
    const float* v_w    = (const float*)d_in[5];
    const float* o_w    = (const float*)d_in[6];
    const float* gate_w = (const float*)d_in[7];
    const float* up_w   = (const float*)d_in[8];
    const float* down_w = (const float*)d_in[9];
    const float* ln1    = (const float*)d_in[10];
    const float* ln2    = (const float*)d_in[11];

    char* w = (char*)d_ws;
    size_t off = 0;
    auto nxt = [&](size_t sz) { char* p = w + off; off += sz; return p; };
    u16*   TQ = (u16*)nxt(13107200);   // q ternary  [2560,2560]   } contiguous => fused
    u16*   TK = (u16*)nxt(3276800);    // k ternary  [640,2560]    }  qkv B-matrix
    u16*   TV = (u16*)nxt(3276800);    // v ternary  [640,2560]    }  [3840,2560]
    u16*   TO = (u16*)nxt(13107200);   // o ternary  [2560,2560]
    u16*   TB = (u16*)nxt(35389440);   // shared big ternary (gate/up/down, quantized just-in-time)
    float* SC = (float*)nxt(91136);    // scales: q@0 k@2560 v@3200 o@3840 g@6400 u@13312 d@20224
    u16*   H  = (u16*)nxt(10485760);   // rmsnorm out bf16 [2048,2560]; reused as attn out and h2
    u16*   QKV = (u16*)nxt(15728640);  // fused qkv proj bf16 [2048,3840] (q|k|v per row)
    u16*   VT = (u16*)nxt(2621440);    // v transposed [5][128][2048]
    float* XM = (float*)nxt(20971520); // x after o-proj residual, fp32 [2048,2560]
    u16*   G  = (u16*)nxt(28311552);   // gate out bf16 [2048,6912]; becomes t in place (MODE2 up)

    // --- attention path ---
    quant_kernel<2, 2><<<2560, 256, 0, stream>>>(q_w, TQ, SC + 0, 2560);
    quant_kernel<2, 2><<<640, 256, 0, stream>>>(k_w, TK, SC + 2560, 2560);
    quant_kernel<2, 2><<<640, 256, 0, stream>>>(v_w, TV, SC + 3200, 2560);
    quant_kernel<2, 2><<<2560, 256, 0, stream>>>(o_w, TO, SC + 3840, 2560);
    rmsnorm_kernel<<<2048, 256, 0, stream>>>(x, ln1, H);
    gemm_bt<0, 2><<<dim3(8, 30), 512, 0, stream>>>(H, TQ, SC + 0, nullptr, QKV, 2048, 3840, 2560);
    rope_kernel<<<10240, 256, 0, stream>>>(QKV, 3840, cosb, sinb, 20);           // q cols 0..2559
    rope_kernel<<<2560, 256, 0, stream>>>(QKV + 2560, 3840, cosb, sinb, 5);      // k cols 2560..3199
    transpose_v_kernel<<<dim3(32, 5), 256, 0, stream>>>(QKV + 3200, 3840, VT);   // v cols 3200..3839
    flash_kernel<<<dim3(32, 20), 256, 0, stream>>>(QKV, 3840, QKV + 2560, VT, H);
    gemm_bt<1, 1><<<dim3(16, 20), 512, 0, stream>>>(H, TO, SC + 3840, x, XM, 2048, 2560, 2560);

    // --- MLP path ---
    rmsnorm_kernel<<<2048, 256, 0, stream>>>(XM, ln2, H);
    quant_kernel<2, 2><<<6912, 256, 0, stream>>>(gate_w, TB, SC + 6400, 2560);
    gemm_bt<0, 2><<<dim3(8, 54), 512, 0, stream>>>(H, TB, SC + 6400, nullptr, G, 2048, 6912, 2560);
    quant_kernel<2, 2><<<6912, 256, 0, stream>>>(up_w, TB, SC + 13312, 2560);
    // up-proj with fused glu epilogue: G[idx] = relu(G[idx])^2 * (acc*scale)
    gemm_bt<2, 2><<<dim3(8, 54), 512, 0, stream>>>(H, TB, SC + 13312, (const float*)G, G, 2048, 6912, 2560);
    quant_kernel<6, 3><<<2560, 256, 0, stream>>>(down_w, TB, SC + 20224, 6912);
    gemm_bt<1, 1><<<dim3(16, 20), 512, 0, stream>>>(G, TB, SC + 20224, XM, (float*)d_out, 2048, 2560, 6912);
}

// Round 7
// 857.801 us; speedup vs baseline: 1.0065x; 1.0052x over previous
//
#include <hip/hip_runtime.h>
#include <hip/hip_bf16.h>

typedef unsigned short u16;
typedef short bf16x8 __attribute__((ext_vector_type(8)));
typedef float f32x4 __attribute__((ext_vector_type(4)));
typedef float f32x16 __attribute__((ext_vector_type(16)));
typedef float f4 __attribute__((ext_vector_type(4)));
typedef unsigned short u16x4 __attribute__((ext_vector_type(4)));

__device__ __forceinline__ u16 f2b(float f) {
    union { __hip_bfloat16 h; u16 u; } cv;
    cv.h = __float2bfloat16(f);
    return cv.u;
}
__device__ __forceinline__ float b2f(u16 u) {
    union { u16 u; __hip_bfloat16 h; } cv;
    cv.u = u;
    return __bfloat162float(cv.h);
}

// async 16B/lane global->LDS. lds base must be wave-uniform; HW scatters lane i to base + i*16.
__device__ __forceinline__ void g2l16(const void* g, void* l) {
    __builtin_amdgcn_global_load_lds(
        (const __attribute__((address_space(1))) unsigned int*)g,
        (__attribute__((address_space(3))) unsigned int*)l, 16, 0, 0);
}

// ---------------- weight ternarization: per-row absmean + ternary bf16 ----------------
// One wave per row (4 rows/block), K = NF4*256 f32. Pass 1: f4 loads + wave shfl reduce
// (no barrier, no LDS). Pass 2: re-read (L2-hot) + ternarize + u16x4 stores.
template <int NF4>
__global__ __launch_bounds__(256) void quant_kernel(const float* __restrict__ W,
                                                    u16* __restrict__ T,
                                                    float* __restrict__ scales, int K) {
    const int wid = threadIdx.x >> 6, lane = threadIdx.x & 63;
    const int row = blockIdx.x * 4 + wid;
    const float* wr = W + (size_t)row * K;
    float s = 0.f;
#pragma unroll
    for (int j = 0; j < NF4; ++j) {
        const f4 v = ((const f4*)wr)[lane + j * 64];
        s += fabsf(v[0]) + fabsf(v[1]) + fabsf(v[2]) + fabsf(v[3]);
    }
#pragma unroll
    for (int d = 1; d < 64; d <<= 1) s += __shfl_xor(s, d);
    const float absmean = s / (float)K;
    const float thr = 0.7f * absmean;
    u16* tr = T + (size_t)row * K;
#pragma unroll
    for (int j = 0; j < NF4; ++j) {
        const f4 v = ((const f4*)wr)[lane + j * 64];
        u16x4 o;
#pragma unroll
        for (int e = 0; e < 4; ++e)
            o[e] = (fabsf(v[e]) > thr) ? ((v[e] > 0.f) ? (u16)0x3F80 : (u16)0xBF80) : (u16)0;
        ((u16x4*)tr)[lane + j * 64] = o;
    }
    if (lane == 0) scales[row] = absmean;
}

// ---------------- rmsnorm: fp32 in -> bf16 out, row = 2560 (2x float4 + 2 scalar) ----------------
__global__ __launch_bounds__(256) void rmsnorm_kernel(const float* __restrict__ x,
                                                      const float* __restrict__ g,
                                                      u16* __restrict__ o) {
    const int row = blockIdx.x, tid = threadIdx.x;
    const float* xr = x + (size_t)row * 2560;
    f4 v[2];
    float vs[2];
    float s = 0.f;
#pragma unroll
    for (int j = 0; j < 2; ++j) {
        v[j] = ((const f4*)xr)[tid + j * 256];
#pragma unroll
        for (int e = 0; e < 4; ++e) s += v[j][e] * v[j][e];
    }
#pragma unroll
    for (int j = 0; j < 2; ++j) { vs[j] = xr[2048 + j * 256 + tid]; s += vs[j] * vs[j]; }
#pragma unroll
    for (int d = 1; d < 64; d <<= 1) s += __shfl_xor(s, d);
    __shared__ float red[4];
    if ((tid & 63) == 0) red[tid >> 6] = s;
    __syncthreads();
    const float total = red[0] + red[1] + red[2] + red[3];
    const float rs = rsqrtf(total * (1.f / 2560.f) + 1e-5f);
    u16* orow = o + (size_t)row * 2560;
#pragma unroll
    for (int j = 0; j < 2; ++j) {
        const f4 gv = ((const f4*)g)[tid + j * 256];
        u16x4 ov;
#pragma unroll
        for (int e = 0; e < 4; ++e) ov[e] = f2b(v[j][e] * rs * gv[e]);
        ((u16x4*)orow)[tid + j * 256] = ov;
    }
#pragma unroll
    for (int j = 0; j < 2; ++j)
        orow[2048 + j * 256 + tid] = f2b(vs[j] * rs * g[2048 + j * 256 + tid]);
}

// ---------------- GEMM: C[M,N] = A[M,K](bf16) x B[N,K](bf16 ternary, B^T layout) ----------------
// 512 threads, 128x128 tile, BK=64, wave tile 64x32 via 2x mfma_f32_32x32x16_bf16.
// v6b: COUNTED-vmcnt 2-deep pipeline (guide T4/m218): double-buffered LDS, raw s_barrier,
// s_waitcnt vmcnt(4) instead of the __syncthreads vmcnt(0) drain. Tile t+1's 4
// global_load_lds stay in flight across BOTH barriers while tile t computes; vmcnt only
// fully drains in the epilogue. Invariant at iter t entry: 8 outstanding (tiles t, t+1);
// vmcnt(4) -> tile t landed (each wave waits its own 4; barrier joins all waves).
// lgkmcnt(0)+barrier after compute releases buf[t&1] (WAR) before stage(t+2) refills it.
// sched_barrier(0) after each inline waitcnt pins compiler ordering (guide rule #18).
// Critical for down-proj: grid 320 on 256 CUs = ~1 block/CU -> no cross-block TLP;
// intra-block pipelining is the only latency cover.
// A/B frag: row/col = lane&31, k = (lane>>5)*8 + j. C/D: col = lane&31,
// row = (reg&3) + 8*(reg>>2) + 4*(lane>>5)  [HW-verified mapping].
// Chunk-XOR-swizzled LDS: elem (row,k) at row*64 + ((k>>3)^(row&7))*8 + (k&7).
// XCD-chunked block swizzle (all grids %8==0) keeps same-B-panel blocks per XCD L2.
// MODE 0: out bf16 = acc*scale[n].  MODE 1: out fp32 = res + acc*scale[n].
// MODE 2: out bf16 = relu(resg)^2 * acc*scale[n]  (glu fused into up-proj; resg = gate bf16).
template <int MODE>
__global__ __launch_bounds__(512, 4) void gemm_bt(const u16* __restrict__ A,
                                                  const u16* __restrict__ B,
                                                  const float* __restrict__ scale,
                                                  const float* res,
                                                  void* __restrict__ outp,
                                                  int M, int N, int K) {
    __shared__ __align__(16) u16 sA[2][128 * 64];
    __shared__ __align__(16) u16 sB[2][128 * 64];
    const int tid = threadIdx.x;
    const int wave = tid >> 6, lane = tid & 63;
    const int l31 = lane & 31, half = lane >> 5;

    // XCD-chunked bijective swizzle (nwg % 8 == 0 for every grid we launch)
    const int nwg = gridDim.x * gridDim.y;
    int lin = blockIdx.y * gridDim.x + blockIdx.x;
    lin = (lin & 7) * (nwg >> 3) + (lin >> 3);
    const int m0 = (lin % gridDim.x) * 128, n0 = (lin / gridDim.x) * 128;
    const int wm = wave >> 2, wn = wave & 3;  // wave tile: rows wm*64+, cols wn*32+

    f32x16 acc[2] = {};

    // staging: instr s covers 64 rows; chunk = s*512 + wave*64 + lane
    // row = s*64 + wave*8 + (lane>>3); phys chunk = lane&7; global chunk = (lane&7)^(row&7)
    const int r0 = wave * 8 + (lane >> 3);           // row&7 == lane>>3
    const int gcc = (lane & 7) ^ (lane >> 3);
    const size_t aoff = (size_t)(m0 + r0) * K + gcc * 8;
    const size_t boff = (size_t)(n0 + r0) * K + gcc * 8;
    const int swz = l31 & 7;  // fragment-read swizzle key (row&7 == l31&7)
    const int arow0 = (wm * 64 + l31) * 64;
    const int arow1 = (wm * 64 + 32 + l31) * 64;
    const int brow = (wn * 32 + l31) * 64;

    auto stage = [&](int kt, int b) {
        char* la = (char*)(&sA[b][0]) + wave * 1024;
        char* lb = (char*)(&sB[b][0]) + wave * 1024;
        g2l16(A + aoff + kt, la);
        g2l16(A + aoff + (size_t)64 * K + kt, la + 8192);
        g2l16(B + boff + kt, lb);
        g2l16(B + boff + (size_t)64 * K + kt, lb + 8192);
    };
    auto compute = [&](int b) {
        const u16* pA = &sA[b][0];
        const u16* pB = &sB[b][0];
#pragma unroll
        for (int ks = 0; ks < 4; ++ks) {
            const int pc = ((ks * 2 + half) ^ swz) * 8;
            const bf16x8 bfr = *(const bf16x8*)&pB[brow + pc];
            const bf16x8 a0 = *(const bf16x8*)&pA[arow0 + pc];
            const bf16x8 a1 = *(const bf16x8*)&pA[arow1 + pc];
            acc[0] = __builtin_amdgcn_mfma_f32_32x32x16_bf16(a0, bfr, acc[0], 0, 0, 0);
            acc[1] = __builtin_amdgcn_mfma_f32_32x32x16_bf16(a1, bfr, acc[1], 0, 0, 0);
        }
    };

    const int nk = K >> 6;  // >= 40 for every launch
    stage(0, 0);
    stage(64, 1);
    for (int t = 0; t < nk - 1; ++t) {
        asm volatile("s_waitcnt vmcnt(4)" ::: "memory");   // tile t landed; t+1 stays in flight
        __builtin_amdgcn_sched_barrier(0);
        __builtin_amdgcn_s_barrier();
        compute(t & 1);
        asm volatile("s_waitcnt lgkmcnt(0)" ::: "memory"); // this wave's reads of buf done
        __builtin_amdgcn_sched_barrier(0);
        __builtin_amdgcn_s_barrier();                      // all waves done -> buf reusable
        if (t + 2 < nk) stage((t + 2) * 64, t & 1);
    }
    asm volatile("s_waitcnt vmcnt(0)" ::: "memory");
    __builtin_amdgcn_sched_barrier(0);
    __builtin_amdgcn_s_barrier();
    compute((nk - 1) & 1);

    const int c = n0 + wn * 32 + l31;
    const float sc = scale[c];
#pragma unroll
    for (int mt = 0; mt < 2; ++mt) {
        const int rb = m0 + wm * 64 + mt * 32 + 4 * half;
#pragma unroll
        for (int r = 0; r < 16; ++r) {
            const int row = rb + (r & 3) + 8 * (r >> 2);
            const float vv = acc[mt][r] * sc;
            const size_t idx = (size_t)row * N + c;
            if (MODE == 0)      ((u16*)outp)[idx] = f2b(vv);
            else if (MODE == 1) ((float*)outp)[idx] = res[idx] + vv;
            else {
                const float gg = fmaxf(b2f(((const u16*)res)[idx]), 0.f);
                ((u16*)outp)[idx] = f2b(gg * gg * vv);
            }
        }
    }
}

// ---------------- RoPE in-place on [2048, stride] bf16, nh heads at given base ----------------
__global__ __launch_bounds__(256) void rope_kernel(u16* __restrict__ buf, int stride,
                                                   const float* __restrict__ cs,
                                                   const float* __restrict__ sn, int nh) {
    const int idx = blockIdx.x * 256 + threadIdx.x;
    const int d = idx & 63;
    const int h = (idx >> 6) % nh;
    const int s = idx / (64 * nh);
    const size_t base = (size_t)s * stride + h * 128;
    const float a = b2f(buf[base + d]), b = b2f(buf[base + d + 64]);
    const float c1 = cs[s * 128 + d], s1 = sn[s * 128 + d];
    const float c2 = cs[s * 128 + d + 64], s2 = sn[s * 128 + d + 64];
    buf[base + d] = f2b(a * c1 - b * s1);
    buf[base + d + 64] = f2b(b * c2 + a * s2);
}

// ---------------- V transpose: [2048, stride] (head h at col h*128) -> [5][128][2048] ----------------
__global__ __launch_bounds__(256) void transpose_v_kernel(const u16* __restrict__ V, int stride,
                                                          u16* __restrict__ VT) {
    __shared__ u16 t[128 * 66];
    const int tid = threadIdx.x;
    const int h = blockIdx.y, s0 = blockIdx.x * 64;
#pragma unroll
    for (int i = 0; i < 32; ++i) {
        const int idx = tid + i * 256;  // 64 s-rows x 128 d
        const int r = idx >> 7, c = idx & 127;
        t[c * 66 + r] = V[(size_t)(s0 + r) * stride + h * 128 + c];
    }
    __syncthreads();
#pragma unroll
    for (int i = 0; i < 32; ++i) {
        const int idx = tid + i * 256;  // 128 d-rows x 64 s
        const int d = idx >> 6, s = idx & 63;
        VT[((size_t)h * 128 + d) * 2048 + s0 + s] = t[d * 66 + s];
    }
}

// ---------------- flash attention: 20 heads, GQA 4:1, S=2048, D=128, non-causal ----------------
// 64 q-rows/block (wave owns 16), 32-key tiles, exp2-domain online softmax.
// Double-buffered K/V at 32-key granularity: total LDS 48KB -> 3 blocks/CU. Prefetch of
// tile t+1 issued before compute of tile t; single end-of-tile barrier.
// Softmax: per-lane partial denominators + defer-max (THR=8 exp2 domain). P at row
// stride 40 u16. NO XCD swizzle (round-4: concentrating same-head blocks on one XCD cut
// FETCH 2.3x but slowed 5% — L2 serialization; default mapping wins).
__global__ __launch_bounds__(256, 3) void flash_kernel(const u16* __restrict__ Q, int qs,
                                                       const u16* __restrict__ Kb,
                                                       const u16* __restrict__ VT,
                                                       u16* __restrict__ O) {
    __shared__ __align__(16) u16 sQ[64 * 128];     // 16KB; reused as sP (64 rows, stride 40)
    __shared__ __align__(16) u16 sK[2][32 * 128];  // 2x8KB
    __shared__ __align__(16) u16 sV[2][128 * 32];  // 2x8KB, V^T tile [d][key]
    const int tid = threadIdx.x, wave = tid >> 6, lane = tid & 63;
    const int lane15 = lane & 15, quad = lane >> 4;
    const int head = blockIdx.y, q0 = blockIdx.x * 64, kvh = head >> 2;
    const int sw = lane15 & 7;

    const int rk = wave * 4 + (lane >> 4);
    const int gk = (lane & 15) ^ (rk & 7);
    const u16* kbase = Kb + (size_t)rk * qs + kvh * 128 + gk * 8;
    const int rv = wave * 16 + (lane >> 2);
    const int gv = (lane & 3) ^ ((lane >> 3) & 3);
    const u16* vbase = VT + ((size_t)kvh * 128 + rv) * 2048 + gv * 8;

    auto stage = [&](int k0, int b) {
        char* dK = (char*)(&sK[b][0]) + wave * 1024;
        char* dV = (char*)(&sV[b][0]) + wave * 1024;
#pragma unroll
        for (int s = 0; s < 2; ++s) {
            g2l16(kbase + ((size_t)k0 + s * 16) * qs, dK + s * 4096);
            g2l16(vbase + (size_t)s * 64 * 2048 + k0, dV + s * 4096);
        }
    };

    {   // stage Q + first K/V tile together (one exposed latency event)
        const int rq = wave * 4 + (lane >> 4);
        const int gq = (lane & 15) ^ (rq & 7);
        const u16* src = Q + (size_t)(q0 + rq) * qs + head * 128 + gq * 8;
        char* dst = (char*)sQ + wave * 1024;
#pragma unroll
        for (int s = 0; s < 4; ++s)
            g2l16(src + (size_t)s * 16 * qs, dst + s * 4096);
        stage(0, 0);
    }
    __syncthreads();
    bf16x8 qf[4];
#pragma unroll
    for (int kc = 0; kc < 4; ++kc)
        qf[kc] = *(const bf16x8*)&sQ[(wave * 16 + lane15) * 128 + ((kc * 4 + quad) ^ sw) * 8];

    float m_i[4], lp[4];
    f32x4 o_acc[8] = {};
#pragma unroll
    for (int r = 0; r < 4; ++r) { m_i[r] = -1e30f; lp[r] = 0.f; }

    const float sl2e = 0.088388347648318447f * 1.4426950408889634f;  // 1/sqrt(128) * log2(e)
    const float THR = 8.0f;  // defer-max threshold (exp2 domain)
    u16* sP = sQ;  // P tile: 64 rows x 32 keys, stride 40 u16 (5120B, fits in sQ)

    for (int t = 0; t < 64; ++t) {
        const int buf = t & 1;
        if (t < 63) stage((t + 1) * 32, buf ^ 1);  // prefetch next tile; drains at the barrier
        const u16* sKb = &sK[buf][0];
        const u16* sVb = &sV[buf][0];

        // S = Q K^T : wave's 16 q-rows x 32 keys
        f32x4 sacc[2] = {};
        __builtin_amdgcn_s_setprio(1);
#pragma unroll
        for (int nf = 0; nf < 2; ++nf)
#pragma unroll
            for (int kc = 0; kc < 4; ++kc) {
                const bf16x8 kf = *(const bf16x8*)&sKb[(nf * 16 + lane15) * 128 + ((kc * 4 + quad) ^ sw) * 8];
                sacc[nf] = __builtin_amdgcn_mfma_f32_16x16x32_bf16(qf[kc], kf, sacc[nf], 0, 0, 0);
            }
        __builtin_amdgcn_s_setprio(0);

        float mx[4];
#pragma unroll
        for (int r = 0; r < 4; ++r) {
            float v0 = sacc[0][r] * sl2e, v1 = sacc[1][r] * sl2e;
            sacc[0][r] = v0; sacc[1][r] = v1;
            float m0 = fmaxf(v0, v1);
#pragma unroll
            for (int d = 1; d < 16; d <<= 1) m0 = fmaxf(m0, __shfl_xor(m0, d));
            mx[r] = m0;
        }
        const int upd = (mx[0] > m_i[0] + THR) | (mx[1] > m_i[1] + THR) |
                        (mx[2] > m_i[2] + THR) | (mx[3] > m_i[3] + THR);
        if (__any(upd)) {
#pragma unroll
            for (int r = 0; r < 4; ++r) {
                const float mnew = fmaxf(m_i[r], mx[r]);
                const float alpha = exp2f(m_i[r] - mnew);
                m_i[r] = mnew;
                lp[r] *= alpha;
#pragma unroll
                for (int nf = 0; nf < 8; ++nf) o_acc[nf][r] *= alpha;
            }
        }
#pragma unroll
        for (int r = 0; r < 4; ++r) {
            const float m = m_i[r];
            const float p0 = exp2f(sacc[0][r] - m), p1 = exp2f(sacc[1][r] - m);
            sacc[0][r] = p0; sacc[1][r] = p1;
            lp[r] += p0 + p1;
        }

        // P -> sP (own 16 rows; same-wave DS ops are ordered). Linear cols, stride 40.
#pragma unroll
        for (int nf = 0; nf < 2; ++nf) {
            const int pcol = nf * 16 + lane15;
#pragma unroll
            for (int r = 0; r < 4; ++r)
                sP[(wave * 16 + quad * 4 + r) * 40 + pcol] = f2b(sacc[nf][r]);
        }

        // O += P V
        const bf16x8 pf = *(const bf16x8*)&sP[(wave * 16 + lane15) * 40 + quad * 8];
        __builtin_amdgcn_s_setprio(1);
#pragma unroll
        for (int nf = 0; nf < 8; ++nf) {
            const bf16x8 vf = *(const bf16x8*)&sVb[(nf * 16 + lane15) * 32 +
                                                   ((quad ^ ((lane15 >> 1) & 3))) * 8];
            o_acc[nf] = __builtin_amdgcn_mfma_f32_16x16x32_bf16(pf, vf, o_acc[nf], 0, 0, 0);
        }
        __builtin_amdgcn_s_setprio(0);
        __syncthreads();
    }

#pragma unroll
    for (int r = 0; r < 4; ++r) {
        float lt = lp[r];
#pragma unroll
        for (int d = 1; d < 16; d <<= 1) lt += __shfl_xor(lt, d);
        const float inv = 1.f / lt;
        const int row = q0 + wave * 16 + quad * 4 + r;
        u16* orow = O + (size_t)row * 2560 + head * 128;
#pragma unroll
        for (int nf = 0; nf < 8; ++nf)
            orow[nf * 16 + lane15] = f2b(o_acc[nf][r] * inv);
    }
}

extern "C" void kernel_launch(void* const* d_in, const int* in_sizes, int n_in,
                              void* d_out, int out_size, void* d_ws, size_t ws_size,
                              hipStream_t stream) {
    (void)in_sizes; (void)n_in; (void)out_size; (void)ws_size;
    const float* x      = (const float*)d_in[0];
    const float* cosb   = (const float*)d_in[1];
    const float* sinb   = (const float*)d_in[2];
    const float* q_w    = (const float*)d_in[3];
    const float* k_w    = (const float*)d_in[4];
    const float* v_w    = (const float*)d_in[5];
    const float* o_w    = (const float*)d_in[6];
    const float* gate_w = (const float*)d_in[7];
    const float* up_w   = (const float*)d_in[8];
    const float* down_w = (const float*)d_in[9];
    const float* ln1    = (const float*)d_in[10];
    const float* ln2    = (const float*)d_in[11];

    char* w = (char*)d_ws;
    size_t off = 0;
    auto nxt = [&](size_t sz) { char* p = w + off; off += sz; return p; };
    u16*   TQ = (u16*)nxt(13107200);   // q ternary  [2560,2560]   } contiguous => fused
    u16*   TK = (u16*)nxt(3276800);    // k ternary  [640,2560]    }  qkv B-matrix
    u16*   TV = (u16*)nxt(3276800);    // v ternary  [640,2560]    }  [3840,2560]
    u16*   TO = (u16*)nxt(13107200);   // o ternary  [2560,2560]
    u16*   TB = (u16*)nxt(35389440);   // shared big ternary (gate/up/down, quantized just-in-time)
    float* SC = (float*)nxt(91136);    // scales: q@0 k@2560 v@3200 o@3840 g@6400 u@13312 d@20224
    u16*   H  = (u16*)nxt(10485760);   // rmsnorm out bf16 [2048,2560]; reused as attn out and h2
    u16*   QKV = (u16*)nxt(15728640);  // fused qkv proj bf16 [2048,3840] (q|k|v per row)
    u16*   VT = (u16*)nxt(2621440);    // v transposed [5][128][2048]
    float* XM = (float*)nxt(20971520); // x after o-proj residual, fp32 [2048,2560]
    u16*   G  = (u16*)nxt(28311552);   // gate out bf16 [2048,6912]; becomes t in place (MODE2 up)

    // --- attention path ---
    quant_kernel<10><<<640, 256, 0, stream>>>(q_w, TQ, SC + 0, 2560);
    quant_kernel<10><<<160, 256, 0, stream>>>(k_w, TK, SC + 2560, 2560);
    quant_kernel<10><<<160, 256, 0, stream>>>(v_w, TV, SC + 3200, 2560);
    quant_kernel<10><<<640, 256, 0, stream>>>(o_w, TO, SC + 3840, 2560);
    rmsnorm_kernel<<<2048, 256, 0, stream>>>(x, ln1, H);
    gemm_bt<0><<<dim3(16, 30), 512, 0, stream>>>(H, TQ, SC + 0, nullptr, QKV, 2048, 3840, 2560);
    rope_kernel<<<10240, 256, 0, stream>>>(QKV, 3840, cosb, sinb, 20);           // q cols 0..2559
    rope_kernel<<<2560, 256, 0, stream>>>(QKV + 2560, 3840, cosb, sinb, 5);      // k cols 2560..3199
    transpose_v_kernel<<<dim3(32, 5), 256, 0, stream>>>(QKV + 3200, 3840, VT);   // v cols 3200..3839
    flash_kernel<<<dim3(32, 20), 256, 0, stream>>>(QKV, 3840, QKV + 2560, VT, H);
    gemm_bt<1><<<dim3(16, 20), 512, 0, stream>>>(H, TO, SC + 3840, x, XM, 2048, 2560, 2560);

    // --- MLP path ---
    rmsnorm_kernel<<<2048, 256, 0, stream>>>(XM, ln2, H);
    quant_kernel<10><<<1728, 256, 0, stream>>>(gate_w, TB, SC + 6400, 2560);
    gemm_bt<0><<<dim3(16, 54), 512, 0, stream>>>(H, TB, SC + 6400, nullptr, G, 2048, 6912, 2560);
    quant_kernel<10><<<1728, 256, 0, stream>>>(up_w, TB, SC + 13312, 2560);
    // up-proj with fused glu epilogue: G[idx] = relu(G[idx])^2 * (acc*scale)
    gemm_bt<2><<<dim3(16, 54), 512, 0, stream>>>(H, TB, SC + 13312, (const float*)G, G, 2048, 6912, 2560);
    quant_kernel<27><<<640, 256, 0, stream>>>(down_w, TB, SC + 20224, 6912);
    gemm_bt<1><<<dim3(16, 20), 512, 0, stream>>>(G, TB, SC + 20224, XM, (float*)d_out, 2048, 2560, 6912);
}

// Round 8
// 822.284 us; speedup vs baseline: 1.0500x; 1.0432x over previous
//
#include <hip/hip_runtime.h>
#include <hip/hip_bf16.h>

typedef unsigned short u16;
typedef short bf16x8 __attribute__((ext_vector_type(8)));
typedef float f32x4 __attribute__((ext_vector_type(4)));
typedef float f4 __attribute__((ext_vector_type(4)));
typedef unsigned short u16x4 __attribute__((ext_vector_type(4)));

__device__ __forceinline__ u16 f2b(float f) {
    union { __hip_bfloat16 h; u16 u; } cv;
    cv.h = __float2bfloat16(f);
    return cv.u;
}
__device__ __forceinline__ float b2f(u16 u) {
    union { u16 u; __hip_bfloat16 h; } cv;
    cv.u = u;
    return __bfloat162float(cv.h);
}

// async 16B/lane global->LDS. lds base must be wave-uniform; HW scatters lane i to base + i*16.
__device__ __forceinline__ void g2l16(const void* g, void* l) {
    __builtin_amdgcn_global_load_lds(
        (const __attribute__((address_space(1))) unsigned int*)g,
        (__attribute__((address_space(3))) unsigned int*)l, 16, 0, 0);
}

// ---------------- weight ternarization: per-row absmean + ternary bf16 ----------------
// One wave per row (4 rows/block), K = NF4*256 f32. Pass 1: f4 loads + wave shfl reduce
// (no barrier, no LDS). Pass 2: re-read (L2-hot) + ternarize + u16x4 stores.
template <int NF4>
__global__ __launch_bounds__(256) void quant_kernel(const float* __restrict__ W,
                                                    u16* __restrict__ T,
                                                    float* __restrict__ scales, int K) {
    const int wid = threadIdx.x >> 6, lane = threadIdx.x & 63;
    const int row = blockIdx.x * 4 + wid;
    const float* wr = W + (size_t)row * K;
    float s = 0.f;
#pragma unroll
    for (int j = 0; j < NF4; ++j) {
        const f4 v = ((const f4*)wr)[lane + j * 64];
        s += fabsf(v[0]) + fabsf(v[1]) + fabsf(v[2]) + fabsf(v[3]);
    }
#pragma unroll
    for (int d = 1; d < 64; d <<= 1) s += __shfl_xor(s, d);
    const float absmean = s / (float)K;
    const float thr = 0.7f * absmean;
    u16* tr = T + (size_t)row * K;
#pragma unroll
    for (int j = 0; j < NF4; ++j) {
        const f4 v = ((const f4*)wr)[lane + j * 64];
        u16x4 o;
#pragma unroll
        for (int e = 0; e < 4; ++e)
            o[e] = (fabsf(v[e]) > thr) ? ((v[e] > 0.f) ? (u16)0x3F80 : (u16)0xBF80) : (u16)0;
        ((u16x4*)tr)[lane + j * 64] = o;
    }
    if (lane == 0) scales[row] = absmean;
}

// ---------------- rmsnorm: fp32 in -> bf16 out, row = 2560 (2x float4 + 2 scalar) ----------------
__global__ __launch_bounds__(256) void rmsnorm_kernel(const float* __restrict__ x,
                                                      const float* __restrict__ g,
                                                      u16* __restrict__ o) {
    const int row = blockIdx.x, tid = threadIdx.x;
    const float* xr = x + (size_t)row * 2560;
    f4 v[2];
    float vs[2];
    float s = 0.f;
#pragma unroll
    for (int j = 0; j < 2; ++j) {
        v[j] = ((const f4*)xr)[tid + j * 256];
#pragma unroll
        for (int e = 0; e < 4; ++e) s += v[j][e] * v[j][e];
    }
#pragma unroll
    for (int j = 0; j < 2; ++j) { vs[j] = xr[2048 + j * 256 + tid]; s += vs[j] * vs[j]; }
#pragma unroll
    for (int d = 1; d < 64; d <<= 1) s += __shfl_xor(s, d);
    __shared__ float red[4];
    if ((tid & 63) == 0) red[tid >> 6] = s;
    __syncthreads();
    const float total = red[0] + red[1] + red[2] + red[3];
    const float rs = rsqrtf(total * (1.f / 2560.f) + 1e-5f);
    u16* orow = o + (size_t)row * 2560;
#pragma unroll
    for (int j = 0; j < 2; ++j) {
        const f4 gv = ((const f4*)g)[tid + j * 256];
        u16x4 ov;
#pragma unroll
        for (int e = 0; e < 4; ++e) ov[e] = f2b(v[j][e] * rs * gv[e]);
        ((u16x4*)orow)[tid + j * 256] = ov;
    }
#pragma unroll
    for (int j = 0; j < 2; ++j)
        orow[2048 + j * 256 + tid] = f2b(vs[j] * rs * g[2048 + j * 256 + tid]);
}

// ---------------- GEMM: C[M,N] = A[M,K](bf16) x B[N,K](bf16 ternary, B^T layout) ----------------
// 512 threads, 128x128 tile, BK=64, wave sub-tile 64x32 via 16x16x32 MFMA (4x2 frags).
// v8: REVERT to 16x16 fragments. The 32x32 switch (round 3) made each ds_read_b128 a
// structural 4-way bank conflict: lane l31<32 reads row l31 at one 16B k-chunk; row
// stride 128B = full bank rotation, so rows 8-apart alias -> 32 rows / 8 chunk slots =
// 4-way (measured: exactly 4.0 conflict-cycles per read, 13.27M/dispatch, const since r3).
// 16x16 frags: only 16 rows share a k-chunk -> 2-way = free (m136). No chunk-XOR can fix
// the 32x32 case (3-bit chunk space can't absorb 2 more row bits).
// Pipeline (from v6b, kept): counted-vmcnt 2-deep dbuf. s_waitcnt vmcnt(4) keeps tile
// t+1's 4 global_load_lds in flight across both barriers while tile t computes; drain
// only in epilogue. lgkmcnt(0)+barrier releases the buffer (WAR) before restaging.
// sched_barrier(0) after each waitcnt pins compiler ordering (guide rule #18).
// 16x16 frag: A row=lane&15(+f*16), k=(lane>>4)*8+j; C/D col=lane&15, row=quad*4+r.
// Chunk-XOR-swizzled LDS: elem (row,k) at row*64 + ((k>>3)^(row&7))*8 + (k&7).
// XCD-chunked block swizzle (all grids %8==0) keeps same-B-panel blocks per XCD L2.
// MODE 0: out bf16 = acc*scale[n].  MODE 1: out fp32 = res + acc*scale[n].
// MODE 2: out bf16 = relu(resg)^2 * acc*scale[n]  (glu fused into up-proj; resg = gate bf16).
template <int MODE>
__global__ __launch_bounds__(512, 4) void gemm_bt(const u16* __restrict__ A,
                                                  const u16* __restrict__ B,
                                                  const float* __restrict__ scale,
                                                  const float* res,
                                                  void* __restrict__ outp,
                                                  int M, int N, int K) {
    __shared__ __align__(16) u16 sA[2][128 * 64];
    __shared__ __align__(16) u16 sB[2][128 * 64];
    const int tid = threadIdx.x;
    const int wave = tid >> 6, lane = tid & 63;
    const int lane15 = lane & 15, quad = lane >> 4;

    // XCD-chunked bijective swizzle (nwg % 8 == 0 for every grid we launch)
    const int nwg = gridDim.x * gridDim.y;
    int lin = blockIdx.y * gridDim.x + blockIdx.x;
    lin = (lin & 7) * (nwg >> 3) + (lin >> 3);
    const int m0 = (lin % gridDim.x) * 128, n0 = (lin / gridDim.x) * 128;
    const int wm = wave >> 2, wn = wave & 3;  // wave tile: rows wm*64+, cols wn*32+

    f32x4 acc[4][2] = {};

    // staging: instr s covers 64 rows; chunk = s*512 + wave*64 + lane
    // row = s*64 + wave*8 + (lane>>3); phys chunk = lane&7; global chunk = (lane&7)^(row&7)
    const int r0 = wave * 8 + (lane >> 3);           // row&7 == lane>>3
    const int gcc = (lane & 7) ^ (lane >> 3);
    const size_t aoff = (size_t)(m0 + r0) * K + gcc * 8;
    const size_t boff = (size_t)(n0 + r0) * K + gcc * 8;
    const int sw = lane15 & 7;  // fragment-read swizzle key (row&7 == lane15&7)

    auto stage = [&](int kt, int b) {
        char* la = (char*)(&sA[b][0]) + wave * 1024;
        char* lb = (char*)(&sB[b][0]) + wave * 1024;
        g2l16(A + aoff + kt, la);
        g2l16(A + aoff + (size_t)64 * K + kt, la + 8192);
        g2l16(B + boff + kt, lb);
        g2l16(B + boff + (size_t)64 * K + kt, lb + 8192);
    };
    auto compute = [&](int b) {
        const u16* pA = &sA[b][0];
        const u16* pB = &sB[b][0];
#pragma unroll
        for (int kc = 0; kc < 2; ++kc) {
            const int pc = ((kc * 4 + quad) ^ sw) * 8;
            bf16x8 af[4], bfr[2];
#pragma unroll
            for (int f = 0; f < 4; ++f)
                af[f] = *(const bf16x8*)&pA[(wm * 64 + f * 16 + lane15) * 64 + pc];
#pragma unroll
            for (int f = 0; f < 2; ++f)
                bfr[f] = *(const bf16x8*)&pB[(wn * 32 + f * 16 + lane15) * 64 + pc];
#pragma unroll
            for (int i = 0; i < 4; ++i)
#pragma unroll
                for (int j = 0; j < 2; ++j)
                    acc[i][j] = __builtin_amdgcn_mfma_f32_16x16x32_bf16(af[i], bfr[j], acc[i][j], 0, 0, 0);
        }
    };

    const int nk = K >> 6;  // >= 40 for every launch
    stage(0, 0);
    stage(64, 1);
    for (int t = 0; t < nk - 1; ++t) {
        asm volatile("s_waitcnt vmcnt(4)" ::: "memory");   // tile t landed; t+1 stays in flight
        __builtin_amdgcn_sched_barrier(0);
        __builtin_amdgcn_s_barrier();
        compute(t & 1);
        asm volatile("s_waitcnt lgkmcnt(0)" ::: "memory"); // this wave's reads of buf done
        __builtin_amdgcn_sched_barrier(0);
        __builtin_amdgcn_s_barrier();                      // all waves done -> buf reusable
        if (t + 2 < nk) stage((t + 2) * 64, t & 1);
    }
    asm volatile("s_waitcnt vmcnt(0)" ::: "memory");
    __builtin_amdgcn_sched_barrier(0);
    __builtin_amdgcn_s_barrier();
    compute((nk - 1) & 1);

#pragma unroll
    for (int j = 0; j < 2; ++j) {
        const int c = n0 + wn * 32 + j * 16 + lane15;
        const float sc = scale[c];
#pragma unroll
        for (int i = 0; i < 4; ++i) {
            const int rbase = m0 + wm * 64 + i * 16 + quad * 4;
#pragma unroll
            for (int r = 0; r < 4; ++r) {
                const float vv = acc[i][j][r] * sc;
                const size_t idx = (size_t)(rbase + r) * N + c;
                if (MODE == 0)      ((u16*)outp)[idx] = f2b(vv);
                else if (MODE == 1) ((float*)outp)[idx] = res[idx] + vv;
                else {
                    const float gg = fmaxf(b2f(((const u16*)res)[idx]), 0.f);
                    ((u16*)outp)[idx] = f2b(gg * gg * vv);
                }
            }
        }
    }
}

// ---------------- RoPE in-place on [2048, stride] bf16, nh heads at given base ----------------
__global__ __launch_bounds__(256) void rope_kernel(u16* __restrict__ buf, int stride,
                                                   const float* __restrict__ cs,
                                                   const float* __restrict__ sn, int nh) {
    const int idx = blockIdx.x * 256 + threadIdx.x;
    const int d = idx & 63;
    const int h = (idx >> 6) % nh;
    const int s = idx / (64 * nh);
    const size_t base = (size_t)s * stride + h * 128;
    const float a = b2f(buf[base + d]), b = b2f(buf[base + d + 64]);
    const float c1 = cs[s * 128 + d], s1 = sn[s * 128 + d];
    const float c2 = cs[s * 128 + d + 64], s2 = sn[s * 128 + d + 64];
    buf[base + d] = f2b(a * c1 - b * s1);
    buf[base + d + 64] = f2b(b * c2 + a * s2);
}

// ---------------- V transpose: [2048, stride] (head h at col h*128) -> [5][128][2048] ----------------
__global__ __launch_bounds__(256) void transpose_v_kernel(const u16* __restrict__ V, int stride,
                                                          u16* __restrict__ VT) {
    __shared__ u16 t[128 * 66];
    const int tid = threadIdx.x;
    const int h = blockIdx.y, s0 = blockIdx.x * 64;
#pragma unroll
    for (int i = 0; i < 32; ++i) {
        const int idx = tid + i * 256;  // 64 s-rows x 128 d
        const int r = idx >> 7, c = idx & 127;
        t[c * 66 + r] = V[(size_t)(s0 + r) * stride + h * 128 + c];
    }
    __syncthreads();
#pragma unroll
    for (int i = 0; i < 32; ++i) {
        const int idx = tid + i * 256;  // 128 d-rows x 64 s
        const int d = idx >> 6, s = idx & 63;
        VT[((size_t)h * 128 + d) * 2048 + s0 + s] = t[d * 66 + s];
    }
}

// ---------------- flash attention: 20 heads, GQA 4:1, S=2048, D=128, non-causal ----------------
// 64 q-rows/block (wave owns 16), 32-key tiles, exp2-domain online softmax.
// Double-buffered K/V at 32-key granularity: total LDS 48KB -> 3 blocks/CU. Prefetch of
// tile t+1 issued before compute of tile t; single end-of-tile barrier.
// Softmax: per-lane partial denominators + defer-max (THR=8 exp2 domain). P at row
// stride 40 u16. NO XCD swizzle (round-4: concentrating same-head blocks on one XCD cut
// FETCH 2.3x but slowed 5% — L2 serialization; default mapping wins).
__global__ __launch_bounds__(256, 3) void flash_kernel(const u16* __restrict__ Q, int qs,
                                                       const u16* __restrict__ Kb,
                                                       const u16* __restrict__ VT,
                                                       u16* __restrict__ O) {
    __shared__ __align__(16) u16 sQ[64 * 128];     // 16KB; reused as sP (64 rows, stride 40)
    __shared__ __align__(16) u16 sK[2][32 * 128];  // 2x8KB
    __shared__ __align__(16) u16 sV[2][128 * 32];  // 2x8KB, V^T tile [d][key]
    const int tid = threadIdx.x, wave = tid >> 6, lane = tid & 63;
    const int lane15 = lane & 15, quad = lane >> 4;
    const int head = blockIdx.y, q0 = blockIdx.x * 64, kvh = head >> 2;
    const int sw = lane15 & 7;

    const int rk = wave * 4 + (lane >> 4);
    const int gk = (lane & 15) ^ (rk & 7);
    const u16* kbase = Kb + (size_t)rk * qs + kvh * 128 + gk * 8;
    const int rv = wave * 16 + (lane >> 2);
    const int gv = (lane & 3) ^ ((lane >> 3) & 3);
    const u16* vbase = VT + ((size_t)kvh * 128 + rv) * 2048 + gv * 8;

    auto stage = [&](int k0, int b) {
        char* dK = (char*)(&sK[b][0]) + wave * 1024;
        char* dV = (char*)(&sV[b][0]) + wave * 1024;
#pragma unroll
        for (int s = 0; s < 2; ++s) {
            g2l16(kbase + ((size_t)k0 + s * 16) * qs, dK + s * 4096);
            g2l16(vbase + (size_t)s * 64 * 2048 + k0, dV + s * 4096);
        }
    };

    {   // stage Q + first K/V tile together (one exposed latency event)
        const int rq = wave * 4 + (lane >> 4);
        const int gq = (lane & 15) ^ (rq & 7);
        const u16* src = Q + (size_t)(q0 + rq) * qs + head * 128 + gq * 8;
        char* dst = (char*)sQ + wave * 1024;
#pragma unroll
        for (int s = 0; s < 4; ++s)
            g2l16(src + (size_t)s * 16 * qs, dst + s * 4096);
        stage(0, 0);
    }
    __syncthreads();
    bf16x8 qf[4];
#pragma unroll
    for (int kc = 0; kc < 4; ++kc)
        qf[kc] = *(const bf16x8*)&sQ[(wave * 16 + lane15) * 128 + ((kc * 4 + quad) ^ sw) * 8];

    float m_i[4], lp[4];
    f32x4 o_acc[8] = {};
#pragma unroll
    for (int r = 0; r < 4; ++r) { m_i[r] = -1e30f; lp[r] = 0.f; }

    const float sl2e = 0.088388347648318447f * 1.4426950408889634f;  // 1/sqrt(128) * log2(e)
    const float THR = 8.0f;  // defer-max threshold (exp2 domain)
    u16* sP = sQ;  // P tile: 64 rows x 32 keys, stride 40 u16 (5120B, fits in sQ)

    for (int t = 0; t < 64; ++t) {
        const int buf = t & 1;
        if (t < 63) stage((t + 1) * 32, buf ^ 1);  // prefetch next tile; drains at the barrier
        const u16* sKb = &sK[buf][0];
        const u16* sVb = &sV[buf][0];

        // S = Q K^T : wave's 16 q-rows x 32 keys
        f32x4 sacc[2] = {};
        __builtin_amdgcn_s_setprio(1);
#pragma unroll
        for (int nf = 0; nf < 2; ++nf)
#pragma unroll
            for (int kc = 0; kc < 4; ++kc) {
                const bf16x8 kf = *(const bf16x8*)&sKb[(nf * 16 + lane15) * 128 + ((kc * 4 + quad) ^ sw) * 8];
                sacc[nf] = __builtin_amdgcn_mfma_f32_16x16x32_bf16(qf[kc], kf, sacc[nf], 0, 0, 0);
            }
        __builtin_amdgcn_s_setprio(0);

        float mx[4];
#pragma unroll
        for (int r = 0; r < 4; ++r) {
            float v0 = sacc[0][r] * sl2e, v1 = sacc[1][r] * sl2e;
            sacc[0][r] = v0; sacc[1][r] = v1;
            float m0 = fmaxf(v0, v1);
#pragma unroll
            for (int d = 1; d < 16; d <<= 1) m0 = fmaxf(m0, __shfl_xor(m0, d));
            mx[r] = m0;
        }
        const int upd = (mx[0] > m_i[0] + THR) | (mx[1] > m_i[1] + THR) |
                        (mx[2] > m_i[2] + THR) | (mx[3] > m_i[3] + THR);
        if (__any(upd)) {
#pragma unroll
            for (int r = 0; r < 4; ++r) {
                const float mnew = fmaxf(m_i[r], mx[r]);
                const float alpha = exp2f(m_i[r] - mnew);
                m_i[r] = mnew;
                lp[r] *= alpha;
#pragma unroll
                for (int nf = 0; nf < 8; ++nf) o_acc[nf][r] *= alpha;
            }
        }
#pragma unroll
        for (int r = 0; r < 4; ++r) {
            const float m = m_i[r];
            const float p0 = exp2f(sacc[0][r] - m), p1 = exp2f(sacc[1][r] - m);
            sacc[0][r] = p0; sacc[1][r] = p1;
            lp[r] += p0 + p1;
        }

        // P -> sP (own 16 rows; same-wave DS ops are ordered). Linear cols, stride 40.
#pragma unroll
        for (int nf = 0; nf < 2; ++nf) {
            const int pcol = nf * 16 + lane15;
#pragma unroll
            for (int r = 0; r < 4; ++r)
                sP[(wave * 16 + quad * 4 + r) * 40 + pcol] = f2b(sacc[nf][r]);
        }

        // O += P V
        const bf16x8 pf = *(const bf16x8*)&sP[(wave * 16 + lane15) * 40 + quad * 8];
        __builtin_amdgcn_s_setprio(1);
#pragma unroll
        for (int nf = 0; nf < 8; ++nf) {
            const bf16x8 vf = *(const bf16x8*)&sVb[(nf * 16 + lane15) * 32 +
                                                   ((quad ^ ((lane15 >> 1) & 3))) * 8];
            o_acc[nf] = __builtin_amdgcn_mfma_f32_16x16x32_bf16(pf, vf, o_acc[nf], 0, 0, 0);
        }
        __builtin_amdgcn_s_setprio(0);
        __syncthreads();
    }

#pragma unroll
    for (int r = 0; r < 4; ++r) {
        float lt = lp[r];
#pragma unroll
        for (int d = 1; d < 16; d <<= 1) lt += __shfl_xor(lt, d);
        const float inv = 1.f / lt;
        const int row = q0 + wave * 16 + quad * 4 + r;
        u16* orow = O + (size_t)row * 2560 + head * 128;
#pragma unroll
        for (int nf = 0; nf < 8; ++nf)
            orow[nf * 16 + lane15] = f2b(o_acc[nf][r] * inv);
    }
}

extern "C" void kernel_launch(void* const* d_in, const int* in_sizes, int n_in,
                              void* d_out, int out_size, void* d_ws, size_t ws_size,
                              hipStream_t stream) {
    (void)in_sizes; (void)n_in; (void)out_size; (void)ws_size;
    const float* x      = (const float*)d_in[0];
    const float* cosb   = (const float*)d_in[1];
    const float* sinb   = (const float*)d_in[2];
    const float* q_w    = (const float*)d_in[3];
    const float* k_w    = (const float*)d_in[4];
    const float* v_w    = (const float*)d_in[5];
    const float* o_w    = (const float*)d_in[6];
    const float* gate_w = (const float*)d_in[7];
    const float* up_w   = (const float*)d_in[8];
    const float* down_w = (const float*)d_in[9];
    const float* ln1    = (const float*)d_in[10];
    const float* ln2    = (const float*)d_in[11];

    char* w = (char*)d_ws;
    size_t off = 0;
    auto nxt = [&](size_t sz) { char* p = w + off; off += sz; return p; };
    u16*   TQ = (u16*)nxt(13107200);   // q ternary  [2560,2560]   } contiguous => fused
    u16*   TK = (u16*)nxt(3276800);    // k ternary  [640,2560]    }  qkv B-matrix
    u16*   TV = (u16*)nxt(3276800);    // v ternary  [640,2560]    }  [3840,2560]
    u16*   TO = (u16*)nxt(13107200);   // o ternary  [2560,2560]
    u16*   TB = (u16*)nxt(35389440);   // shared big ternary (gate/up/down, quantized just-in-time)
    float* SC = (float*)nxt(91136);    // scales: q@0 k@2560 v@3200 o@3840 g@6400 u@13312 d@20224
    u16*   H  = (u16*)nxt(10485760);   // rmsnorm out bf16 [2048,2560]; reused as attn out and h2
    u16*   QKV = (u16*)nxt(15728640);  // fused qkv proj bf16 [2048,3840] (q|k|v per row)
    u16*   VT = (u16*)nxt(2621440);    // v transposed [5][128][2048]
    float* XM = (float*)nxt(20971520); // x after o-proj residual, fp32 [2048,2560]
    u16*   G  = (u16*)nxt(28311552);   // gate out bf16 [2048,6912]; becomes t in place (MODE2 up)

    // --- attention path ---
    quant_kernel<10><<<640, 256, 0, stream>>>(q_w, TQ, SC + 0, 2560);
    quant_kernel<10><<<160, 256, 0, stream>>>(k_w, TK, SC + 2560, 2560);
    quant_kernel<10><<<160, 256, 0, stream>>>(v_w, TV, SC + 3200, 2560);
    quant_kernel<10><<<640, 256, 0, stream>>>(o_w, TO, SC + 3840, 2560);
    rmsnorm_kernel<<<2048, 256, 0, stream>>>(x, ln1, H);
    gemm_bt<0><<<dim3(16, 30), 512, 0, stream>>>(H, TQ, SC + 0, nullptr, QKV, 2048, 3840, 2560);
    rope_kernel<<<10240, 256, 0, stream>>>(QKV, 3840, cosb, sinb, 20);           // q cols 0..2559
    rope_kernel<<<2560, 256, 0, stream>>>(QKV + 2560, 3840, cosb, sinb, 5);      // k cols 2560..3199
    transpose_v_kernel<<<dim3(32, 5), 256, 0, stream>>>(QKV + 3200, 3840, VT);   // v cols 3200..3839
    flash_kernel<<<dim3(32, 20), 256, 0, stream>>>(QKV, 3840, QKV + 2560, VT, H);
    gemm_bt<1><<<dim3(16, 20), 512, 0, stream>>>(H, TO, SC + 3840, x, XM, 2048, 2560, 2560);

    // --- MLP path ---
    rmsnorm_kernel<<<2048, 256, 0, stream>>>(XM, ln2, H);
    quant_kernel<10><<<1728, 256, 0, stream>>>(gate_w, TB, SC + 6400, 2560);
    gemm_bt<0><<<dim3(16, 54), 512, 0, stream>>>(H, TB, SC + 6400, nullptr, G, 2048, 6912, 2560);
    quant_kernel<10><<<1728, 256, 0, stream>>>(up_w, TB, SC + 13312, 2560);
    // up-proj with fused glu epilogue: G[idx] = relu(G[idx])^2 * (acc*scale)
    gemm_bt<2><<<dim3(16, 54), 512, 0, stream>>>(H, TB, SC + 13312, (const float*)G, G, 2048, 6912, 2560);
    quant_kernel<27><<<640, 256, 0, stream>>>(down_w, TB, SC + 20224, 6912);
    gemm_bt<1><<<dim3(16, 20), 512, 0, stream>>>(G, TB, SC + 20224, XM, (float*)d_out, 2048, 2560, 6912);
}